// Round 7
// baseline (2108.623 us; speedup 1.0000x reference)
//
#include <hip/hip_runtime.h>

#define NROWS 8192
#define RPB   64
#define TPB   512
#define NBLK  128

// workspace layout (float offsets)
#define OFF_W1   0          // 1024
#define OFF_W2   1024       // 1024
#define OFF_WIN  2048       // 102*34 = 3468
#define OFF_WFC2 5516       // 1024
#define OFF_M    6540       // 32*34 = 1088
#define OFF_B12  7628       // 32
#define OFF_BIN  7660       // 102
#define OFF_B2   7762       // 32
#define OFF_BFC2 7794       // 32
#define OFF_LNG  7826       // 32
#define OFF_LNB  7858       // 32
#define OFF_QKV0 8192
#define QKVN     (NROWS*102)          // feature-major: qkv[e][row]
#define OFF_QKV1 (OFF_QKV0 + QKVN)
#define OFF_HNEW (OFF_QKV1 + QKVN)   // feature-major: hnew[j][row], 32*NROWS
#define OFF_RDY  (OFF_HNEW + 32*NROWS)        // 128 flags, stride 32 ints
#define OFF_DONE (OFF_RDY + 4096)             // 128 flags, stride 32 ints
#define FLS      32                            // flag stride (128B, own line)

// ---- coherent (cross-XCD) access helpers: relaxed agent-scope atomics ----
// These compile to sc0/sc1-flagged global ops served at the coherence point:
// per-address coherence WITHOUT buffer_wbl2/buffer_inv cache nukes.
__device__ __forceinline__ float ldc(const float* p) {
  return __hip_atomic_load(p, __ATOMIC_RELAXED, __HIP_MEMORY_SCOPE_AGENT);
}
__device__ __forceinline__ void stc(float* p, float v) {
  __hip_atomic_store(p, v, __ATOMIC_RELAXED, __HIP_MEMORY_SCOPE_AGENT);
}
__device__ __forceinline__ int ldf(const int* p) {
  return __hip_atomic_load(p, __ATOMIC_RELAXED, __HIP_MEMORY_SCOPE_AGENT);
}
__device__ __forceinline__ void stf(int* p, int v) {
  __hip_atomic_store(p, v, __ATOMIC_RELAXED, __HIP_MEMORY_SCOPE_AGENT);
}

__global__ __launch_bounds__(256) void setup_kernel(
    const float* __restrict__ W_x2h, const float* __restrict__ b_x2h,
    const float* __restrict__ W_h2h, const float* __restrict__ b_h2h,
    const float* __restrict__ W_fc2, const float* __restrict__ b_fc2,
    const float* __restrict__ ln_g,  const float* __restrict__ ln_b,
    const float* __restrict__ W_fcsa,const float* __restrict__ b_fcsa,
    const float* __restrict__ W_in,  const float* __restrict__ b_in,
    const float* __restrict__ W_out, const float* __restrict__ b_out,
    float* __restrict__ ws)
{
  int t = blockIdx.x*blockDim.x + threadIdx.x;
  int stride = gridDim.x*blockDim.x;
  for (int i=t;i<8192;i+=stride) ((int*)(ws+OFF_RDY))[i] = 0;   // ready+done flags
  for (int i=t;i<1024;i+=stride) ws[OFF_W1+i]   = W_x2h[i];
  for (int i=t;i<1024;i+=stride) ws[OFF_W2+i]   = W_h2h[i];
  for (int i=t;i<3468;i+=stride) ws[OFF_WIN+i]  = W_in[i];
  for (int i=t;i<1024;i+=stride) ws[OFF_WFC2+i] = W_fc2[i];
  for (int i=t;i<32;i+=stride)   ws[OFF_B12+i]  = b_x2h[i] + b_h2h[i];
  for (int i=t;i<102;i+=stride)  ws[OFF_BIN+i]  = b_in[i];
  for (int i=t;i<32;i+=stride)   ws[OFF_BFC2+i] = b_fc2[i];
  for (int i=t;i<32;i+=stride)   ws[OFF_LNG+i]  = ln_g[i];
  for (int i=t;i<32;i+=stride)   ws[OFF_LNB+i]  = ln_b[i];
  // M = W_fcsa (32x34) @ W_out (34x34)
  for (int idx=t; idx<1088; idx+=stride) {
    int j = idx/34, f = idx - j*34;
    float acc = 0.f;
    for (int e=0;e<34;++e)
      acc += W_fcsa[j*34+e] * W_out[e*34+f];
    ws[OFF_M+idx] = acc;
  }
  for (int j=t;j<32;j+=stride){
    float acc = b_fcsa[j];
    for (int e=0;e<34;++e) acc += W_fcsa[j*34+e] * b_out[e];
    ws[OFF_B2+j] = acc;
  }
}

// Poll a clamped window of flags until all reach target. tid0-only; others
// park at the following __syncthreads. Memory clobber stops the compiler
// hoisting subsequent loads above the poll.
__device__ __forceinline__ void wait_flags(int* flags, int lo, int hi, int target) {
  for (int n = lo; n <= hi; ++n) {
    while (ldf(flags + n*FLS) < target) __builtin_amdgcn_s_sleep(2);
  }
  __asm__ volatile("" ::: "memory");
}

// Persistent kernel, NO global barrier. Block bid owns one grid-row (64 rows).
// Neighbor gather touches grid-rows br-1..br+1 -> only blocks bid-2..bid+2
// (same batch). Producer/consumer sync via per-block epoch flags:
//   ready[n] = s+1  <=> block n's qkv of step s is globally visible
//   done[n]  = i    <=> block n finished all its qkv reads of iteration i
// Consumer (iter i reads qkv(i-1)): wait ready[bid±2] >= i.
// Producer (iter i writes slot i&1, last read during iter i-1): wait done[bid±2] >= i-1.
__global__ __launch_bounds__(TPB) void rnn_all(
    float* __restrict__ ws,
    const float* __restrict__ x,
    float* __restrict__ out)
{
  const float* W1f   = ws + OFF_W1;
  const float* W2f   = ws + OFF_W2;
  const float* Winf  = ws + OFF_WIN;
  const float* Wfc2f = ws + OFF_WFC2;
  const float* Mf    = ws + OFF_M;
  const float* b12f  = ws + OFF_B12;
  const float* binf  = ws + OFF_BIN;
  const float* b2f   = ws + OFF_B2;
  const float* bfc2f = ws + OFF_BFC2;
  const float* lngf  = ws + OFF_LNG;
  const float* lnbf  = ws + OFF_LNB;
  float* hnewG = ws + OFF_HNEW;
  int*   rdyF  = (int*)(ws + OFF_RDY);
  int*   donF  = (int*)(ws + OFF_DONE);

  __shared__ float sS[RPB][13];     // 9 scores
  __shared__ float sO[RPB][35];     // attention output (34)
  __shared__ float sHp[RPB][33];    // h' (post-attention state)
  __shared__ float sG[RPB][33];     // pre-LN fc2 output
  __shared__ float sPred[RPB][33];  // pred (next-step input)
  __shared__ float sHn[RPB][33];    // h_new (tanh output)
  __shared__ float sX[RPB][33];     // staged x chunk (steps 0..9)

  const int tid = threadIdx.x;
  const int lr  = tid & 63;
  const int wu  = __builtin_amdgcn_readfirstlane(tid >> 6);  // wave id, uniform
  const int bid = blockIdx.x;
  const int base= bid * RPB;
  const int r   = base + lr;
  const int b   = r >> 12;
  const int p   = r & 4095;
  const int gr  = p >> 6, gc = p & 63;
  const int br  = (gr < 1) ? 1 : ((gr > 62) ? 62 : gr);
  const int bc  = (gc < 1) ? 1 : ((gc > 62) ? 62 : gc);
  const int qrow = (b<<12) + (br<<6) + bc;           // gathered center row
  // flag wait-window: same-batch blocks within distance 2
  const int bb  = bid & ~63;
  const int wlo = (bid-2 < bb)    ? bb    : bid-2;
  const int whi = (bid+2 > bb+63) ? bb+63 : bid+2;

  for (int i = 0; i < 60; ++i) {
    const int stepB = i - 1;
    const int stepA = (i <= 58) ? i : -1;
    const float* qkvR = ws + OFF_QKV0 + (size_t)((i+1)&1)*QKVN;
    float*       qkvW = ws + OFF_QKV0 + (size_t)(i&1)*QKVN;

    if (stepB >= 0) {
      // ---- consumer wait: neighbors' qkv(stepB) visible ----
      if (tid == 0) wait_flags(rdyF, wlo, whi, i);
      __syncthreads();
      // ---- scores: q loaded once, wave wu does neighbor m=wu (w0 also 8) ----
      {
        float qv[34];
        #pragma unroll
        for (int e=0;e<34;++e) qv[e] = ldc(qkvR + (size_t)e*NROWS + qrow);
        for (int m = wu; m < 9; m += 8) {
          int dr = m/3 - 1, dc = (m - (m/3)*3) - 1;
          int nr_  = (b<<12) + ((br+dr)<<6) + (bc+dc);
          float acc = 0.f;
          #pragma unroll
          for (int e=0;e<34;++e)
            acc += qv[e] * ldc(qkvR + (size_t)(34+e)*NROWS + nr_);
          sS[lr][m] = acc * 0.1714985851425088f;       // 1/sqrt(34)
        }
      }
      __syncthreads();
      // ---- softmax (redundant per wave) + o: wave wu handles e = 5*wu.. ----
      if (wu < 7) {
        float sc[9]; float mx = -1e30f;
        #pragma unroll
        for (int m=0;m<9;++m){ sc[m]=sS[lr][m]; mx=fmaxf(mx,sc[m]); }
        float sum=0.f;
        #pragma unroll
        for (int m=0;m<9;++m){ sc[m]=__expf(sc[m]-mx); sum+=sc[m]; }
        float inv = 1.f/sum;
        const int e0 = wu*5;
        const int ne = (e0+5<=34)?5:(34-e0);
        float oacc[5] = {0.f,0.f,0.f,0.f,0.f};
        #pragma unroll
        for (int m=0;m<9;++m){
          int dr = m/3 - 1, dc = (m - (m/3)*3) - 1;
          int nr_ = (b<<12) + ((br+dr)<<6) + (bc+dc);
          float wm = sc[m]*inv;
          #pragma unroll
          for (int k=0;k<5;++k)
            if (k<ne) oacc[k] += wm * ldc(qkvR + (size_t)(68+e0+k)*NROWS + nr_);
        }
        #pragma unroll
        for (int k=0;k<5;++k) if (k<ne) sO[lr][e0+k]=oacc[k];
      }
      __syncthreads();   // all qkv(stepB) reads complete (vmcnt drained)
      if (tid == 0) stf(donF + bid*FLS, i);   // publish read-completion
      // ---- h' = h_new + o @ M^T + b2 : wave wu -> j = 4wu..4wu+3 ----
      {
        const int j0 = wu*4;
        float a[4];
        #pragma unroll
        for (int jj=0;jj<4;++jj) a[jj] = b2f[j0+jj];
        #pragma unroll
        for (int e=0;e<34;++e){
          float ov = sO[lr][e];
          #pragma unroll
          for (int jj=0;jj<4;++jj) a[jj] += ov * Mf[(j0+jj)*34+e];   // s_load
        }
        #pragma unroll
        for (int jj=0;jj<4;++jj)
          sHp[lr][j0+jj] = hnewG[(size_t)(j0+jj)*NROWS + r] + a[jj];
      }
      __syncthreads();
      // ---- g = h' @ Wfc2^T + b ----
      {
        const int j0 = wu*4;
        float g[4];
        #pragma unroll
        for (int jj=0;jj<4;++jj) g[jj] = bfc2f[j0+jj];
        #pragma unroll
        for (int i2=0;i2<32;++i2){
          float hv = sHp[lr][i2];
          #pragma unroll
          for (int jj=0;jj<4;++jj) g[jj] += hv * Wfc2f[(j0+jj)*32+i2]; // s_load
        }
        #pragma unroll
        for (int jj=0;jj<4;++jj) sG[lr][j0+jj]=g[jj];
      }
      __syncthreads();
      // ---- layernorm -> sPred ----
      {
        float mu=0.f;
        #pragma unroll
        for (int i2=0;i2<32;++i2) mu += sG[lr][i2];
        mu *= 0.03125f;
        float var=0.f;
        #pragma unroll
        for (int i2=0;i2<32;++i2){ float d=sG[lr][i2]-mu; var += d*d; }
        var *= 0.03125f;
        float rs = rsqrtf(var + 1e-5f);
        const int j0 = wu*4;
        #pragma unroll
        for (int jj=0;jj<4;++jj){
          int j=j0+jj;
          sPred[lr][j] = (sG[lr][j]-mu)*rs*lngf[j] + lnbf[j];
        }
      }
      __syncthreads();
      // ---- coalesced out write (block chunk = 2048 contiguous floats) ----
      {
        size_t obase = ((size_t)stepB*NROWS + base)*32;
        #pragma unroll
        for (int it=0; it<4; ++it){
          int idx = tid + it*TPB;
          out[obase + idx] = sPred[idx>>5][idx&31];
        }
      }
    } else {
      const int j0 = wu*4;
      #pragma unroll
      for (int jj=0;jj<4;++jj) sHp[lr][j0+jj]=0.f;
      __syncthreads();
    }

    if (stepA >= 0) {
      // ---- stage x chunk (coalesced) if this step consumes observations ----
      if (stepA < 10) {
        size_t xbase = ((size_t)stepA*NROWS + base)*32;
        #pragma unroll
        for (int it=0; it<4; ++it){
          int idx = tid + it*TPB;
          sX[idx>>5][idx&31] = x[xbase + idx];
        }
      }
      __syncthreads();
      // ---- h_new = tanh(inp@W1^T + h'@W2^T + b) : wave wu -> j=4wu.. ----
      const int j0 = wu*4;
      float a[4];
      #pragma unroll
      for (int jj=0;jj<4;++jj) a[jj]=b12f[j0+jj];
      if (stepA < 10) {
        #pragma unroll
        for (int i2=0;i2<32;++i2){
          float xv=sX[lr][i2], hv=sHp[lr][i2];
          #pragma unroll
          for (int jj=0;jj<4;++jj)
            a[jj] += xv*W1f[(j0+jj)*32+i2] + hv*W2f[(j0+jj)*32+i2];  // s_load
        }
      } else {
        #pragma unroll
        for (int i2=0;i2<32;++i2){
          float xv=sPred[lr][i2], hv=sHp[lr][i2];
          #pragma unroll
          for (int jj=0;jj<4;++jj)
            a[jj] += xv*W1f[(j0+jj)*32+i2] + hv*W2f[(j0+jj)*32+i2];  // s_load
        }
      }
      #pragma unroll
      for (int jj=0;jj<4;++jj){
        float tv = tanhf(a[jj]);
        sHn[lr][j0+jj]=tv;
        hnewG[(size_t)(j0+jj)*NROWS + r]=tv;    // block-local, plain store
      }
      // ---- producer wait: slot (i&1) free (neighbors read qkv(i-2)) ----
      if (tid == 0 && stepA >= 2) wait_flags(donF, wlo, whi, stepA-1);
      __syncthreads();
      // ---- qkv = [h_new, pl] @ W_in^T + b_in : wave wu -> e = 13*wu.. ----
      float hn[32];
      #pragma unroll
      for (int f=0;f<32;++f) hn[f]=sHn[lr][f];
      const float pl0 = gr*0.015625f, pl1 = gc*0.015625f;
      const int e0 = wu*13;
      #pragma unroll
      for (int k=0;k<13;++k){
        int e = e0+k;
        if (e < 102) {
          float acc = binf[e];
          #pragma unroll
          for (int f=0;f<32;++f) acc += hn[f]*Winf[e*34+f];          // s_load
          acc += pl0*Winf[e*34+32] + pl1*Winf[e*34+33];
          stc(qkvW + (size_t)e*NROWS + r, acc);   // coherent, coalesced
        }
      }
      __syncthreads();   // vmcnt drained -> qkv stores acked at coherence point
      if (tid == 0) stf(rdyF + bid*FLS, stepA+1);  // publish qkv(stepA)
    }
  }
}

extern "C" void kernel_launch(void* const* d_in, const int* in_sizes, int n_in,
                              void* d_out, int out_size, void* d_ws, size_t ws_size,
                              hipStream_t stream) {
  const float* x     = (const float*)d_in[0];
  const float* W_x2h = (const float*)d_in[1];
  const float* b_x2h = (const float*)d_in[2];
  const float* W_h2h = (const float*)d_in[3];
  const float* b_h2h = (const float*)d_in[4];
  const float* W_fc2 = (const float*)d_in[5];
  const float* b_fc2 = (const float*)d_in[6];
  const float* ln_g  = (const float*)d_in[7];
  const float* ln_b  = (const float*)d_in[8];
  const float* W_fcsa= (const float*)d_in[9];
  const float* b_fcsa= (const float*)d_in[10];
  const float* W_in  = (const float*)d_in[11];
  const float* b_in  = (const float*)d_in[12];
  const float* W_out = (const float*)d_in[13];
  const float* b_out = (const float*)d_in[14];
  float* ws = (float*)d_ws;
  float* out = (float*)d_out;

  setup_kernel<<<8, 256, 0, stream>>>(W_x2h,b_x2h,W_h2h,b_h2h,W_fc2,b_fc2,ln_g,ln_b,
                                      W_fcsa,b_fcsa,W_in,b_in,W_out,b_out, ws);

  void* args[] = { (void*)&ws, (void*)&x, (void*)&out };
  hipLaunchCooperativeKernel((void*)rnn_all, dim3(NBLK), dim3(TPB), args, 0, stream);
}